// Round 1
// baseline (288.679 us; speedup 1.0000x reference)
//
#include <hip/hip_runtime.h>
#include <math.h>

// critic_attention: B=65536 items, N=16 agents, per-agent feat 40 (32 obs + 8 act)
// layer0: [40]->[64] shared; agent0 -> lrelu (x_self), agents1..15 -> tanh (x_others)
// attention: logits = lrelu(a_self + x_others . W1[64:]), softmax over 15, weighted sum
// then 128->128 lrelu, 128->128 lrelu, 128->1.
//
// Mapping: lane = item. Weights are wave-uniform -> s_load + v_fmac (SGPR operand).
// Per-thread private LDS slice (129-float stride: (t*129+i)%32 = (t+i)%32 -> 2-way
// bank alias = free) holds x_cat then x1 for the rolled-i W2/W3 loops.

#define SLOPE 0.01f
#define LOG2E 1.4426950408889634f

__device__ __forceinline__ float lrelu(float x) {
    return fmaxf(x, SLOPE * x);
}

__device__ __forceinline__ float fast_tanh(float x) {
    // tanh(x) = 1 - 2/(e^{2x}+1);  e^{2x} = 2^{x * 2*log2(e)}
    float e = exp2f(x * (2.0f * LOG2E));
    return 1.0f - __fdividef(2.0f, e + 1.0f);
}

// h[c] += x[f] * W0[f][c] for a chunk of nf4*4 features
__device__ __forceinline__ void accum_w0(float h[64], const float* __restrict__ xptr,
                                         const float* __restrict__ wbase, int nf4) {
    for (int f4 = 0; f4 < nf4; ++f4) {
        float4 xv = *reinterpret_cast<const float4*>(xptr + f4 * 4);
        const float* w = wbase + f4 * 4 * 64;
#pragma unroll
        for (int c = 0; c < 64; ++c) {
            h[c] = fmaf(xv.x, w[c], h[c]);
            h[c] = fmaf(xv.y, w[c + 64], h[c]);
            h[c] = fmaf(xv.z, w[c + 128], h[c]);
            h[c] = fmaf(xv.w, w[c + 192], h[c]);
        }
    }
}

__global__ __launch_bounds__(64) void critic_attention_kernel(
    const float* __restrict__ obs, const float* __restrict__ act,
    const float* __restrict__ W0, const float* __restrict__ b0,
    const float* __restrict__ W1, const float* __restrict__ b1v,
    const float* __restrict__ W2, const float* __restrict__ b2,
    const float* __restrict__ W3, const float* __restrict__ b3,
    const float* __restrict__ Wc, const float* __restrict__ bcv,
    float* __restrict__ out)
{
    __shared__ float lds[64 * 129];
    const int t = threadIdx.x;
    float* slice = lds + t * 129;

    const long item = (long)blockIdx.x * 64 + t;
    const float* orow = obs + item * 512;   // 16 agents * 32
    const float* arow = act + item * 128;   // 16 agents * 8

    float h[64];
    float xsum[64];

    // ---------------- agent 0: x_self ----------------
#pragma unroll
    for (int c = 0; c < 64; ++c) h[c] = b0[c];
    accum_w0(h, orow, W0, 8);
    accum_w0(h, arow, W0 + 32 * 64, 2);

    float a0 = 0.f, a1 = 0.f, a2 = 0.f, a3 = 0.f;
#pragma unroll
    for (int c = 0; c < 64; c += 4) {
        float s0 = lrelu(h[c + 0]);
        float s1 = lrelu(h[c + 1]);
        float s2 = lrelu(h[c + 2]);
        float s3 = lrelu(h[c + 3]);
        slice[c + 0] = s0;   // x_cat[0:64] = x_self
        slice[c + 1] = s1;
        slice[c + 2] = s2;
        slice[c + 3] = s3;
        a0 = fmaf(s0, W1[c + 0], a0);
        a1 = fmaf(s1, W1[c + 1], a1);
        a2 = fmaf(s2, W1[c + 2], a2);
        a3 = fmaf(s3, W1[c + 3], a3);
    }
    const float a_self = b1v[0] + ((a0 + a1) + (a2 + a3));

    // ---------------- agents 1..15: online softmax attention ----------------
    float m = -INFINITY, s = 0.f;
#pragma unroll
    for (int c = 0; c < 64; ++c) xsum[c] = 0.f;

    for (int n = 1; n < 16; ++n) {
#pragma unroll
        for (int c = 0; c < 64; ++c) h[c] = b0[c];
        accum_w0(h, orow + n * 32, W0, 8);
        accum_w0(h, arow + n * 8, W0 + 32 * 64, 2);

        float d0 = 0.f, d1 = 0.f, d2 = 0.f, d3 = 0.f;
#pragma unroll
        for (int c = 0; c < 64; c += 4) {
            h[c + 0] = fast_tanh(h[c + 0]);
            h[c + 1] = fast_tanh(h[c + 1]);
            h[c + 2] = fast_tanh(h[c + 2]);
            h[c + 3] = fast_tanh(h[c + 3]);
            d0 = fmaf(h[c + 0], W1[64 + c + 0], d0);
            d1 = fmaf(h[c + 1], W1[64 + c + 1], d1);
            d2 = fmaf(h[c + 2], W1[64 + c + 2], d2);
            d3 = fmaf(h[c + 3], W1[64 + c + 3], d3);
        }
        float logit = lrelu(a_self + ((d0 + d1) + (d2 + d3)));

        float mn = fmaxf(m, logit);
        float scale = exp2f((m - mn) * LOG2E);   // first iter: exp2(-inf) = 0
        float e = exp2f((logit - mn) * LOG2E);
        s = fmaf(s, scale, e);
        m = mn;
#pragma unroll
        for (int c = 0; c < 64; ++c)
            xsum[c] = fmaf(xsum[c], scale, e * h[c]);
    }

    const float inv_s = __fdividef(1.0f, s);
#pragma unroll
    for (int c = 0; c < 64; ++c) slice[64 + c] = xsum[c] * inv_s;  // x_cat[64:128]

    // ---------------- x1 = lrelu(x_cat @ W2 + b2) ----------------
    float acc[128];
#pragma unroll
    for (int j = 0; j < 128; ++j) acc[j] = b2[j];
    for (int i = 0; i < 128; ++i) {
        float xv = slice[i];
        const float* w = W2 + i * 128;
#pragma unroll
        for (int j = 0; j < 128; ++j) acc[j] = fmaf(xv, w[j], acc[j]);
    }
#pragma unroll
    for (int j = 0; j < 128; ++j) slice[j] = lrelu(acc[j]);  // x1 overwrites x_cat

    // ---------------- x2 = lrelu(x1 @ W3 + b3) ----------------
#pragma unroll
    for (int j = 0; j < 128; ++j) acc[j] = b3[j];
    for (int i = 0; i < 128; ++i) {
        float xv = slice[i];
        const float* w = W3 + i * 128;
#pragma unroll
        for (int j = 0; j < 128; ++j) acc[j] = fmaf(xv, w[j], acc[j]);
    }

    // ---------------- value = x2 @ Wc + bc ----------------
    float v0 = 0.f, v1 = 0.f, v2 = 0.f, v3 = 0.f;
#pragma unroll
    for (int j = 0; j < 128; j += 4) {
        v0 = fmaf(lrelu(acc[j + 0]), Wc[j + 0], v0);
        v1 = fmaf(lrelu(acc[j + 1]), Wc[j + 1], v1);
        v2 = fmaf(lrelu(acc[j + 2]), Wc[j + 2], v2);
        v3 = fmaf(lrelu(acc[j + 3]), Wc[j + 3], v3);
    }
    out[item] = bcv[0] + ((v0 + v1) + (v2 + v3));
}

extern "C" void kernel_launch(void* const* d_in, const int* in_sizes, int n_in,
                              void* d_out, int out_size, void* d_ws, size_t ws_size,
                              hipStream_t stream) {
    (void)in_sizes; (void)n_in; (void)d_ws; (void)ws_size; (void)out_size;
    const float* obs = (const float*)d_in[0];
    const float* act = (const float*)d_in[1];
    const float* W0  = (const float*)d_in[2];
    const float* b0  = (const float*)d_in[3];
    const float* W1  = (const float*)d_in[4];
    const float* b1  = (const float*)d_in[5];
    const float* W2  = (const float*)d_in[6];
    const float* b2  = (const float*)d_in[7];
    const float* W3  = (const float*)d_in[8];
    const float* b3  = (const float*)d_in[9];
    const float* Wc  = (const float*)d_in[10];
    const float* bc  = (const float*)d_in[11];

    critic_attention_kernel<<<dim3(65536 / 64), dim3(64), 0, stream>>>(
        obs, act, W0, b0, W1, b1, W2, b2, W3, b3, Wc, bc, (float*)d_out);
}